// Round 9
// baseline (162.131 us; speedup 1.0000x reference)
//
#include <hip/hip_runtime.h>
#include <stdint.h>

// Problem constants
#define B_   8
#define S_   2047
#define L_   2048      // S+1 (CLS prepended)
#define H_   256       // HIDDEN
#define NH_  8
#define HD_  32
#define V_   32001     // VOCAB+1
#define NCH_ 128       // t-chunks per b
#define TCH_ 16        // t per chunk (NCH_*TCH_ == L_)

__device__ __forceinline__ float foldx(float a, int off) {
    return a + __shfl_xor(a, off, 64);
}
__device__ __forceinline__ float sel8(const float a[8], int j) {
    float v = a[0];
    v = (j == 1) ? a[1] : v;
    v = (j == 2) ? a[2] : v;
    v = (j == 3) ? a[3] : v;
    v = (j == 4) ? a[4] : v;
    v = (j == 5) ? a[5] : v;
    v = (j == 6) ? a[6] : v;
    v = (j == 7) ? a[7] : v;
    return v;
}

// ---------------------------------------------------------------------------
// K0 (grid 8, block per head n): y0 = emb[2]+pe[0]; q0[k] = wq[n,k,:]·y0;
// qk[n][h] = (sum_k q0[k]*wk[n,k,h]) / sqrt(32).  (round-0 verbatim)
// ---------------------------------------------------------------------------
__global__ __launch_bounds__(256) void k0_prep(const float* __restrict__ emb,
                                               const float* __restrict__ wq,
                                               const float* __restrict__ wk,
                                               float* __restrict__ qk) {
    __shared__ float y0_l[H_];
    __shared__ float q0p[HD_][8];
    __shared__ float q0_l[HD_];
    int n = blockIdx.x, tid = threadIdx.x;
    float v = emb[2 * H_ + tid] + ((tid & 1) ? 1.0f : 0.0f);  // pe[0]: sin0/cos0
    y0_l[tid] = v;
    __syncthreads();
    {
        int k = tid >> 3, part = tid & 7;
        const float* w = wq + (n * HD_ + k) * H_ + part * 32;
        const float* yy = y0_l + part * 32;
        float acc = 0.f;
#pragma unroll
        for (int j = 0; j < 32; ++j) acc += w[j] * yy[j];
        q0p[k][part] = acc;
    }
    __syncthreads();
    if (tid < HD_) {
        float s = 0.f;
#pragma unroll
        for (int j = 0; j < 8; ++j) s += q0p[tid][j];
        q0_l[tid] = s;
    }
    __syncthreads();
    float acc = 0.f;
    for (int k = 0; k < HD_; ++k)
        acc += q0_l[k] * wk[(n * HD_ + k) * H_ + tid];
    qk[n * H_ + tid] = acc * 0.17677669529663687f;  // 1/sqrt(32)
}

// ---------------------------------------------------------------------------
// KA (grid 1024 = b*128+c, 4 waves x 4 t): fused scores + ybar contribution.
// Per t: y = emb+pe in fp32 regs; 8 score dots -> 17-shuffle fold -> e;
// acc[n] += e_n * y. Cross-wave LDS reduce, then device atomicAdd into
// obar[b][n][h] / ebar[b][n]. qk read as normal cached float4 (8 KB, L2-hot).
// ---------------------------------------------------------------------------
__global__ __launch_bounds__(256, 4) void kA_scores(const int* __restrict__ x,
                                                    const float* __restrict__ emb,
                                                    const float* __restrict__ qk,
                                                    float* __restrict__ obar,
                                                    float* __restrict__ ebar) {
    int bid = blockIdx.x, tid = threadIdx.x;
    int b = bid >> 7, c = bid & 127;
    int lane = tid & 63, w = tid >> 6;
    int h0 = lane * 4;
    int t0 = c * TCH_ + w * 4;

    __shared__ float red[4][2056];   // 32.9 KB: [wave][n*H+h] + es @2048

    float4 qr[NH_];
#pragma unroll
    for (int n = 0; n < NH_; ++n)
        qr[n] = *(const float4*)(qk + n * H_ + h0);

    int toks[4];
#pragma unroll
    for (int i = 0; i < 4; ++i) {
        int t = t0 + i;
        toks[i] = (t == 0) ? 2 : x[b * S_ + t - 1];
    }
    const float cdiv = 0.07195578414202881f;  // ln(10000)/128
    float div0 = __expf(-(float)(lane * 2) * cdiv);
    float div1 = __expf(-(float)(lane * 2 + 1) * cdiv);

    float4 acc[NH_];
    float es[NH_];
#pragma unroll
    for (int n = 0; n < NH_; ++n) {
        acc[n] = make_float4(0.f, 0.f, 0.f, 0.f);
        es[n] = 0.f;
    }

#pragma unroll
    for (int i = 0; i < 4; ++i) {
        int t = t0 + i;
        float4 ev = *(const float4*)(emb + (size_t)toks[i] * H_ + h0);
        float a0 = (float)t * div0, a1 = (float)t * div1;
        float4 y4;
        y4.x = ev.x + __sinf(a0); y4.y = ev.y + __cosf(a0);
        y4.z = ev.z + __sinf(a1); y4.w = ev.w + __cosf(a1);

        float a[NH_];
#pragma unroll
        for (int n = 0; n < NH_; ++n)
            a[n] = qr[n].x * y4.x + qr[n].y * y4.y + qr[n].z * y4.z + qr[n].w * y4.w;

        float m4[4];
#pragma unroll
        for (int k = 0; k < 4; ++k) {
            float lo = foldx(a[k], 32), hi = foldx(a[k + 4], 32);
            m4[k] = (lane & 32) ? hi : lo;
        }
        float m2[2];
#pragma unroll
        for (int k = 0; k < 2; ++k) {
            float lo = foldx(m4[k], 16), hi = foldx(m4[k + 2], 16);
            m2[k] = (lane & 16) ? hi : lo;
        }
        float lo = foldx(m2[0], 8), hi = foldx(m2[1], 8);
        float m1 = (lane & 8) ? hi : lo;
        m1 = foldx(m1, 4); m1 = foldx(m1, 2); m1 = foldx(m1, 1);
        float e = __expf(m1);  // lane n*8 holds head n's score

#pragma unroll
        for (int n = 0; n < NH_; ++n) {
            float en = __shfl(e, n * 8, 64);
            acc[n].x += en * y4.x; acc[n].y += en * y4.y;
            acc[n].z += en * y4.z; acc[n].w += en * y4.w;
            es[n] += en;
        }
    }

#pragma unroll
    for (int n = 0; n < NH_; ++n)
        *(float4*)&red[w][n * H_ + h0] = acc[n];
    if (lane < NH_) red[w][2048 + lane] = sel8(es, lane);
    __syncthreads();

#pragma unroll
    for (int jj = 0; jj < (NH_ * H_) / 256; ++jj) {
        int j = jj * 256 + tid;
        atomicAdd(obar + b * (NH_ * H_) + j,
                  red[0][j] + red[1][j] + red[2][j] + red[3][j]);
    }
    if (tid < NH_)
        atomicAdd(ebar + b * NH_ + tid,
                  red[0][2048 + tid] + red[1][2048 + tid]
                + red[2][2048 + tid] + red[3][2048 + tid]);
}

// ---------------------------------------------------------------------------
// KB (grid 8 = b): ybar = obar/ebar -> wv -> wo -> z = . + 2*y0
// ---------------------------------------------------------------------------
__global__ __launch_bounds__(256) void kB_proj(const float* __restrict__ emb,
                                               const float* __restrict__ obar,
                                               const float* __restrict__ ebar,
                                               const float* __restrict__ wv,
                                               const float* __restrict__ wo,
                                               float* __restrict__ z) {
    int b = blockIdx.x, tid = threadIdx.x;
    __shared__ float ybar_l[NH_ * H_];   // 8 KB
    __shared__ float o_l[NH_ * HD_];
    __shared__ float sB[NH_];
    if (tid < NH_) sB[tid] = 1.0f / ebar[b * NH_ + tid];
    __syncthreads();
    for (int i = tid; i < NH_ * H_; i += 256)
        ybar_l[i] = obar[b * (NH_ * H_) + i] * sB[i >> 8];
    __syncthreads();
    {   // wv: thread tid = n*32+k computes o[tid]
        int n = tid >> 5;
        const float* wrow = wv + (size_t)tid * H_;
        const float* yy = ybar_l + n * H_;
        float s = 0.f;
#pragma unroll 16
        for (int j4 = 0; j4 < H_ / 4; ++j4) {
            float4 w4 = *(const float4*)(wrow + j4 * 4);
            s += w4.x * yy[j4 * 4] + w4.y * yy[j4 * 4 + 1]
               + w4.z * yy[j4 * 4 + 2] + w4.w * yy[j4 * 4 + 3];
        }
        o_l[tid] = s;
    }
    __syncthreads();
    {   // wo + double residual
        float y0v = emb[2 * H_ + tid] + ((tid & 1) ? 1.0f : 0.0f);
        const float* wrow = wo + (size_t)tid * (NH_ * HD_);
        float s = 0.f;
#pragma unroll 16
        for (int j4 = 0; j4 < (NH_ * HD_) / 4; ++j4) {
            float4 w4 = *(const float4*)(wrow + j4 * 4);
            s += w4.x * o_l[j4 * 4] + w4.y * o_l[j4 * 4 + 1]
               + w4.z * o_l[j4 * 4 + 2] + w4.w * o_l[j4 * 4 + 3];
        }
        z[b * H_ + tid] = s + 2.0f * y0v;
    }
}

// ---------------------------------------------------------------------------
// KC (grid 1001, 32 vocab rows each): out[b,v] = z·wu[v]. z staged in padded
// LDS (normal cached loads, 8 KB L2-hot); 2 passes of 16 rows.
// ---------------------------------------------------------------------------
__global__ __launch_bounds__(256, 4) void kC_out(const float* __restrict__ z,
                                                 const float* __restrict__ wu,
                                                 float* __restrict__ out) {
    int bid = blockIdx.x, tid = threadIdx.x;
    int lane = tid & 63, w = tid >> 6;
    int m = lane & 15, g = lane >> 4;
    int base = bid * 32;

    __shared__ float zs[2560];       // [b*320 + (h>>4)*20 + (h&15)]
    __shared__ float sm_out[B_ * 33];
    for (int i = tid; i < B_ * H_; i += 256) {
        int bb = i >> 8, h = i & 255;
        zs[bb * 320 + (h >> 4) * 20 + (h & 15)] = z[i];
    }
    __syncthreads();

#pragma unroll
    for (int pass = 0; pass < 2; ++pass) {
        int rl = pass * 16 + w * 4 + g;
        int v = base + rl;
        int vc = (v < V_) ? v : (V_ - 1);
        const float* wr = wu + (size_t)vc * H_ + m * 16;
        float4 w0 = *(const float4*)(wr);
        float4 w1 = *(const float4*)(wr + 4);
        float4 w2 = *(const float4*)(wr + 8);
        float4 w3 = *(const float4*)(wr + 12);
        float acc[B_];
#pragma unroll
        for (int bb = 0; bb < B_; ++bb) {
            const float* zb = zs + bb * 320 + m * 20;
            float4 z0 = *(const float4*)(zb);
            float4 z1 = *(const float4*)(zb + 4);
            float4 z2 = *(const float4*)(zb + 8);
            float4 z3 = *(const float4*)(zb + 12);
            acc[bb] = z0.x * w0.x + z0.y * w0.y + z0.z * w0.z + z0.w * w0.w
                    + z1.x * w1.x + z1.y * w1.y + z1.z * w1.z + z1.w * w1.w
                    + z2.x * w2.x + z2.y * w2.y + z2.z * w2.z + z2.w * w2.w
                    + z3.x * w3.x + z3.y * w3.y + z3.z * w3.z + z3.w * w3.w;
        }
#pragma unroll
        for (int off = 1; off <= 8; off <<= 1) {
#pragma unroll
            for (int bb = 0; bb < B_; ++bb) acc[bb] += __shfl_xor(acc[bb], off, 64);
        }
        if (m < B_) sm_out[m * 33 + rl] = sel8(acc, m);
    }
    __syncthreads();
    {
        int bb = tid >> 5, vl = tid & 31, vv = base + vl;
        if (vv < V_) out[bb * V_ + vv] = sm_out[bb * 33 + vl];
    }
}

// ---------------------------------------------------------------------------
extern "C" void kernel_launch(void* const* d_in, const int* in_sizes, int n_in,
                              void* d_out, int out_size, void* d_ws, size_t ws_size,
                              hipStream_t stream) {
    const int*   x   = (const int*)d_in[0];
    const float* emb = (const float*)d_in[1];
    const float* wq  = (const float*)d_in[2];
    const float* wk  = (const float*)d_in[3];
    const float* wv  = (const float*)d_in[4];
    const float* wo  = (const float*)d_in[5];
    const float* wu  = (const float*)d_in[6];
    float*       out = (float*)d_out;

    // ws layout (floats), ~82 KB:
    // qk[2048] | z[2048] | obar[8*2048] | ebar[64]
    float* qk   = (float*)d_ws;
    float* z    = qk + NH_ * H_;
    float* obar = z + B_ * H_;
    float* ebar = obar + B_ * NH_ * H_;

    // Zero the atomic accumulators (workspace is poisoned each iteration).
    hipMemsetAsync(obar, 0, (B_ * NH_ * H_ + B_ * NH_) * sizeof(float), stream);

    k0_prep  <<<8,    256, 0, stream>>>(emb, wq, wk, qk);
    kA_scores<<<1024, 256, 0, stream>>>(x, emb, qk, obar, ebar);
    kB_proj  <<<8,    256, 0, stream>>>(emb, obar, ebar, wv, wo, z);
    kC_out   <<<1001, 256, 0, stream>>>(z, wu, out);
}